// Round 5
// baseline (223.560 us; speedup 1.0000x reference)
//
#include <hip/hip_runtime.h>

// Problem constants
#define NB 16          // batch
#define NV 8           // vars per sample
#define HW 512         // H = W
#define PH 16          // patch h = w
#define GH 32          // grid h = w (512/16)
#define ED 128         // embed dim
#define KD 256         // 16*16 patch elems
#define MAXV 10

typedef __bf16 bf16x8 __attribute__((ext_vector_type(8)));
typedef float  f32x4  __attribute__((ext_vector_type(4)));

// ---------------------------------------------------------------------------
// Pack fp32 weights -> bf16 in B-fragment order:
//   packed[var*32768 + kb*4096 + n*32 + t], k = kb*32 + t, t = quad*8 + j
// (verified correct rounds 1-4)
// ---------------------------------------------------------------------------
__global__ __launch_bounds__(256) void pack_weights(const float* __restrict__ w,
                                                    __bf16* __restrict__ packed) {
    int tid = blockIdx.x * 256 + threadIdx.x;
    if (tid >= MAXV * ED * KD) return;
    int t   = tid & 31;
    int n   = (tid >> 5) & 127;
    int kb  = (tid >> 12) & 7;
    int var = tid >> 15;
    int k   = kb * 32 + t;
    packed[tid] = (__bf16)w[(var * ED + n) * KD + k];
}

// ---------------------------------------------------------------------------
// v5: one WAVE = one full strip (32 patches x 128 emb). No LDS, no barriers,
// no cross-wave A redundancy. Burst-issue the ENTIRE strip (32 x dwordx4 =
// 32 KB/wave) + first B set + bias before any use (asm fence pins issue
// order); the 48 live destination registers ARE the memory-level
// parallelism: 8 waves/CU x 48 KB ~= 384 KB outstanding per CU vs ~9 KB
// needed to saturate this CU's HBM share. Compute (128 MFMA ~ 620 cyc) is
// small vs memory per round, so convoy phasing is harmless. B reloads per
// emb-phase hit L2 (640 KB packed weights) and are covered by other waves.
//
// A-fragment trick (verified R2): for frag (kb,i), lane (lo,quad) needs
// A[m=i*16+lo][k=kb*32+quad*8..+7] = 8 CONSECUTIVE floats of x at
// row 2*kb+(quad>>1), col (i*16+lo)*16 + (quad&1)*8.
// ---------------------------------------------------------------------------
__global__ __launch_bounds__(256, 2) void patch_embed(
    const float* __restrict__ x,
    const int*   __restrict__ in_vars,
    const __bf16* __restrict__ wpacked,
    const float* __restrict__ bias,
    float* __restrict__ out)
{
    const int tid  = threadIdx.x;
    const int wv   = tid >> 6;
    const int lane = tid & 63;
    const int lo   = lane & 15;
    const int quad = lane >> 4;
    const int qh   = quad >> 1;
    const int qlo  = quad & 1;

    // one strip per wave; block's 4 waves take consecutive h of same (b,v)
    const int sid = blockIdx.x * 4 + wv;
    const int h   = sid & 31;
    const int v   = (sid >> 5) & 7;
    const int b   = sid >> 8;

    const int var = in_vars[v];

    const float*  xb    = x + (((size_t)(b * NV + v)) * HW + (size_t)h * PH) * HW;
    const __bf16* wbase = wpacked + (size_t)var * (ED * KD);

    // ---- burst-issue ALL loads: 32x A (full strip) + 16x B(phase0) + bias ----
    float4 a0[8][2], a1[8][2];                       // 128 VGPR, live until cvt
    const float* abase = xb + qh * HW + lo * PH + qlo * 8;
    #pragma unroll
    for (int kb = 0; kb < 8; ++kb)
        #pragma unroll
        for (int i = 0; i < 2; ++i) {
            const float* p = abase + (size_t)(2 * kb) * HW + i * 256;
            a0[kb][i] = *(const float4*)p;
            a1[kb][i] = *(const float4*)(p + 4);
        }

    bf16x8 bF[8][2];                                 // 64 VGPR
    #pragma unroll
    for (int kb = 0; kb < 8; ++kb)
        #pragma unroll
        for (int j = 0; j < 2; ++j)
            bF[kb][j] = *(const bf16x8*)&wbase[kb * 4096 + (j * 16 + lo) * 32 + quad * 8];

    float bv[4][2];
    #pragma unroll
    for (int ph = 0; ph < 4; ++ph)
        #pragma unroll
        for (int j = 0; j < 2; ++j)
            bv[ph][j] = bias[var * ED + ph * 32 + j * 16 + lo];

    asm volatile("" ::: "memory");   // pin: all loads issued before any use

    // ---- cvt full strip to bf16 A-fragments (a0/a1 die here) ----
    bf16x8 aF[8][2];
    #pragma unroll
    for (int kb = 0; kb < 8; ++kb)
        #pragma unroll
        for (int i = 0; i < 2; ++i) {
            bf16x8 t;
            t[0] = (__bf16)a0[kb][i].x; t[1] = (__bf16)a0[kb][i].y;
            t[2] = (__bf16)a0[kb][i].z; t[3] = (__bf16)a0[kb][i].w;
            t[4] = (__bf16)a1[kb][i].x; t[5] = (__bf16)a1[kb][i].y;
            t[6] = (__bf16)a1[kb][i].z; t[7] = (__bf16)a1[kb][i].w;
            aF[kb][i] = t;
        }

    const size_t outbase = ((size_t)(b * NV + v)) * (GH * GH) + (size_t)h * GH;

    // ---- 4 emb-phases: reuse A registers, reload B (L2-hit) per phase ----
    #pragma unroll
    for (int ph = 0; ph < 4; ++ph) {
        if (ph > 0) {
            #pragma unroll
            for (int kb = 0; kb < 8; ++kb)
                #pragma unroll
                for (int j = 0; j < 2; ++j)
                    bF[kb][j] = *(const bf16x8*)&wbase[kb * 4096 + (ph * 32 + j * 16 + lo) * 32 + quad * 8];
        }

        f32x4 acc[2][2];
        #pragma unroll
        for (int i = 0; i < 2; ++i)
            #pragma unroll
            for (int j = 0; j < 2; ++j)
                acc[i][j] = (f32x4){0.f, 0.f, 0.f, 0.f};

        #pragma unroll
        for (int kb = 0; kb < 8; ++kb)
            #pragma unroll
            for (int i = 0; i < 2; ++i)
                #pragma unroll
                for (int j = 0; j < 2; ++j)
                    acc[i][j] = __builtin_amdgcn_mfma_f32_16x16x32_bf16(aF[kb][i], bF[kb][j], acc[i][j], 0, 0, 0);

        // epilogue: C/D layout col = lane&15, row = quad*4 + reg (m89)
        #pragma unroll
        for (int i = 0; i < 2; ++i)
            #pragma unroll
            for (int r = 0; r < 4; ++r) {
                int m = i * 16 + quad * 4 + r;
                #pragma unroll
                for (int j = 0; j < 2; ++j)
                    out[(outbase + m) * ED + ph * 32 + j * 16 + lo] = acc[i][j][r] + bv[ph][j];
            }
    }
}

extern "C" void kernel_launch(void* const* d_in, const int* in_sizes, int n_in,
                              void* d_out, int out_size, void* d_ws, size_t ws_size,
                              hipStream_t stream) {
    const float* x       = (const float*)d_in[0];
    const int*   in_vars = (const int*)d_in[1];
    const float* w       = (const float*)d_in[2];
    const float* bias    = (const float*)d_in[3];
    float*       out     = (float*)d_out;
    __bf16*      wpacked = (__bf16*)d_ws;   // 655,360 B needed

    hipLaunchKernelGGL(pack_weights, dim3((MAXV * ED * KD + 255) / 256), dim3(256), 0, stream,
                       w, wpacked);
    hipLaunchKernelGGL(patch_embed, dim3(NB * NV * GH / 4), dim3(256), 0, stream,
                       x, in_vars, wpacked, bias, out);
}